// Round 1
// baseline (19759.175 us; speedup 1.0000x reference)
//
#include <hip/hip_runtime.h>
#include <stdint.h>

// Problem constants (hardcoded in the reference module)
#define HID 100
#define GATES 400      // 4*H
#define B_TOTAL 512
#define T_IN 1000
#define NB 2           // batch elements per block
#define BLOCK 512

// ---- bf16 pack/unpack (weights only; all state stays fp32) ----
__device__ __forceinline__ uint32_t bf16rne(float f) {
  uint32_t u = __float_as_uint(f);
  return (u + 0x7fffu + ((u >> 16) & 1u)) >> 16;
}
__device__ __forceinline__ uint32_t pack2(float lo, float hi) {
  return bf16rne(lo) | (bf16rne(hi) << 16);
}
__device__ __forceinline__ float ulo(uint32_t p) { return __uint_as_float(p << 16); }
__device__ __forceinline__ float uhi(uint32_t p) { return __uint_as_float(p & 0xffff0000u); }

__device__ __forceinline__ float sigm(float x) { return 1.0f / (1.0f + __expf(-x)); }
__device__ __forceinline__ float tanh_fast(float x) {
  // tanh(x) = 1 - 2/(exp(2x)+1); saturates correctly at +/-inf
  float e = __expf(2.0f * x);
  return 1.0f - 2.0f / (e + 1.0f);
}

__global__ __launch_bounds__(BLOCK, 2) void lstm2_persistent(
    const float* __restrict__ input,  // [512,1000]
    const float* __restrict__ Wih1,   // [400,1]
    const float* __restrict__ Whh1,   // [400,100]
    const float* __restrict__ bih1,
    const float* __restrict__ bhh1,
    const float* __restrict__ Wih2,   // [400,100]
    const float* __restrict__ Whh2,   // [400,100]
    const float* __restrict__ bih2,
    const float* __restrict__ bhh2,
    const float* __restrict__ Wlin,   // [1,100]
    const float* __restrict__ blin,   // [1]
    const int* __restrict__ futp,     // scalar
    float* __restrict__ out)          // [512, 1000+future]
{
  __shared__ float xrow[NB][T_IN];   // staged input rows  (8000 B)
  __shared__ float h1s[NB][HID];     // layer-1 hidden     (800 B)
  __shared__ float h2s[NB][HID];     // layer-2 hidden     (800 B)
  __shared__ float gb[NB][GATES];    // gate staging       (3200 B)
  __shared__ float pb[NB][HID];      // y partial products (800 B)
  __shared__ float yb[NB];           // y feedback

  const int tid = threadIdx.x;
  const int b0 = blockIdx.x * NB;
  const int F = futp[0];
  const int TT = T_IN + F;

  // ---- stage input rows into LDS (read 1300x later) ----
  for (int i = tid; i < NB * T_IN; i += BLOCK) {
    int b = i / T_IN, t = i % T_IN;
    xrow[b][t] = input[(size_t)(b0 + b) * T_IN + t];
  }
  for (int i = tid; i < NB * HID; i += BLOCK) {
    ((float*)h1s)[i] = 0.0f;
    ((float*)h2s)[i] = 0.0f;
  }

  // ---- register-stationary weights: thread j owns row j of all 3 matrices ----
  uint32_t w[150];  // [0:50)=Whh1 row, [50:100)=Wih2 row, [100:150)=Whh2 row (bf16x2)
  float wih1_j = 0.0f, b1j = 0.0f, b2j = 0.0f;
  const int j = tid;
  if (j < GATES) {
    wih1_j = Wih1[j];
    b1j = bih1[j] + bhh1[j];
    b2j = bih2[j] + bhh2[j];
    const float4* r1 = (const float4*)(Whh1 + j * HID);  // j*400B: 16B aligned
    const float4* r2 = (const float4*)(Wih2 + j * HID);
    const float4* r3 = (const float4*)(Whh2 + j * HID);
#pragma unroll
    for (int q = 0; q < 25; q++) {
      float4 v = r1[q];
      w[2 * q] = pack2(v.x, v.y);
      w[2 * q + 1] = pack2(v.z, v.w);
    }
#pragma unroll
    for (int q = 0; q < 25; q++) {
      float4 v = r2[q];
      w[50 + 2 * q] = pack2(v.x, v.y);
      w[50 + 2 * q + 1] = pack2(v.z, v.w);
    }
#pragma unroll
    for (int q = 0; q < 25; q++) {
      float4 v = r3[q];
      w[100 + 2 * q] = pack2(v.x, v.y);
      w[100 + 2 * q + 1] = pack2(v.z, v.w);
    }
  }

  // ---- activation role: (b=0,k)=threads 0..99 ; (b=1,k)=threads 256..355 ----
  int actb = -1, actk = 0;
  if (tid < HID) { actb = 0; actk = tid; }
  else if (tid >= 256 && tid < 256 + HID) { actb = 1; actk = tid - 256; }
  float wlin_k = (actb >= 0) ? Wlin[actk] : 0.0f;
  const float blin0 = blin[0];
  float c1 = 0.0f, c2 = 0.0f;  // cell state lives in act-thread registers

  __syncthreads();

  for (int t = 0; t < TT; t++) {
    float x0, x1;
    if (t < T_IN) { x0 = xrow[0][t]; x1 = xrow[1][t]; }
    else          { x0 = yb[0];      x1 = yb[1];      }

    // ---------- layer 1 gates: g1[j] = x*Wih1[j] + h1 . Whh1[j,:] + b1[j]
    if (j < GATES) {
      float a0 = fmaf(x0, wih1_j, b1j);
      float a1 = fmaf(x1, wih1_j, b1j);
      const float4* hA = (const float4*)h1s[0];
      const float4* hB = (const float4*)h1s[1];
#pragma unroll
      for (int q = 0; q < 25; q++) {
        uint32_t pA = w[2 * q], pB = w[2 * q + 1];
        float w0 = ulo(pA), w1 = uhi(pA), w2 = ulo(pB), w3 = uhi(pB);
        float4 hv0 = hA[q], hv1 = hB[q];  // LDS broadcast reads
        a0 = fmaf(w0, hv0.x, a0); a0 = fmaf(w1, hv0.y, a0);
        a0 = fmaf(w2, hv0.z, a0); a0 = fmaf(w3, hv0.w, a0);
        a1 = fmaf(w0, hv1.x, a1); a1 = fmaf(w1, hv1.y, a1);
        a1 = fmaf(w2, hv1.z, a1); a1 = fmaf(w3, hv1.w, a1);
      }
      gb[0][j] = a0;
      gb[1][j] = a1;
    }
    __syncthreads();

    // ---------- layer 1 activations -> h1
    if (actb >= 0) {
      float gi = gb[actb][actk];
      float gf = gb[actb][actk + 100];
      float gg = gb[actb][actk + 200];
      float go = gb[actb][actk + 300];
      c1 = sigm(gf) * c1 + sigm(gi) * tanh_fast(gg);
      h1s[actb][actk] = sigm(go) * tanh_fast(c1);
    }
    __syncthreads();

    // ---------- layer 2 gates: g2[j] = h1 . Wih2[j,:] + h2 . Whh2[j,:] + b2[j]
    if (j < GATES) {
      float a0 = b2j, a1 = b2j;
      const float4* hA = (const float4*)h1s[0];
      const float4* hB = (const float4*)h1s[1];
      const float4* hC = (const float4*)h2s[0];
      const float4* hD = (const float4*)h2s[1];
#pragma unroll
      for (int q = 0; q < 25; q++) {
        uint32_t pA = w[50 + 2 * q], pB = w[50 + 2 * q + 1];
        float w0 = ulo(pA), w1 = uhi(pA), w2 = ulo(pB), w3 = uhi(pB);
        float4 hv0 = hA[q], hv1 = hB[q];
        a0 = fmaf(w0, hv0.x, a0); a0 = fmaf(w1, hv0.y, a0);
        a0 = fmaf(w2, hv0.z, a0); a0 = fmaf(w3, hv0.w, a0);
        a1 = fmaf(w0, hv1.x, a1); a1 = fmaf(w1, hv1.y, a1);
        a1 = fmaf(w2, hv1.z, a1); a1 = fmaf(w3, hv1.w, a1);
      }
#pragma unroll
      for (int q = 0; q < 25; q++) {
        uint32_t pA = w[100 + 2 * q], pB = w[100 + 2 * q + 1];
        float w0 = ulo(pA), w1 = uhi(pA), w2 = ulo(pB), w3 = uhi(pB);
        float4 hv0 = hC[q], hv1 = hD[q];
        a0 = fmaf(w0, hv0.x, a0); a0 = fmaf(w1, hv0.y, a0);
        a0 = fmaf(w2, hv0.z, a0); a0 = fmaf(w3, hv0.w, a0);
        a1 = fmaf(w0, hv1.x, a1); a1 = fmaf(w1, hv1.y, a1);
        a1 = fmaf(w2, hv1.z, a1); a1 = fmaf(w3, hv1.w, a1);
      }
      gb[0][j] = a0;
      gb[1][j] = a1;
    }
    __syncthreads();

    // ---------- layer 2 activations -> h2, y partials
    if (actb >= 0) {
      float gi = gb[actb][actk];
      float gf = gb[actb][actk + 100];
      float gg = gb[actb][actk + 200];
      float go = gb[actb][actk + 300];
      c2 = sigm(gf) * c2 + sigm(gi) * tanh_fast(gg);
      float h2v = sigm(go) * tanh_fast(c2);
      h2s[actb][actk] = h2v;
      pb[actb][actk] = h2v * wlin_k;
    }
    __syncthreads();

    // ---------- y = sum(pb) + blin ; store + feed back
    if (tid == 0 || tid == 256) {
      int b = (tid == 0) ? 0 : 1;
      const float4* pv = (const float4*)pb[b];
      float s0 = 0.f, s1 = 0.f, s2 = 0.f, s3 = 0.f;
#pragma unroll
      for (int q = 0; q < 25; q++) {
        float4 v = pv[q];
        s0 += v.x; s1 += v.y; s2 += v.z; s3 += v.w;
      }
      float y = (s0 + s1) + (s2 + s3) + blin0;
      yb[b] = y;
      out[(size_t)(b0 + b) * TT + t] = y;
    }
    __syncthreads();
  }
}

extern "C" void kernel_launch(void* const* d_in, const int* in_sizes, int n_in,
                              void* d_out, int out_size, void* d_ws, size_t ws_size,
                              hipStream_t stream) {
  const float* input = (const float*)d_in[0];
  const float* Wih1  = (const float*)d_in[1];
  const float* Whh1  = (const float*)d_in[2];
  const float* bih1  = (const float*)d_in[3];
  const float* bhh1  = (const float*)d_in[4];
  const float* Wih2  = (const float*)d_in[5];
  const float* Whh2  = (const float*)d_in[6];
  const float* bih2  = (const float*)d_in[7];
  const float* bhh2  = (const float*)d_in[8];
  const float* Wlin  = (const float*)d_in[9];
  const float* blin  = (const float*)d_in[10];
  const int*   futp  = (const int*)d_in[11];
  float* out = (float*)d_out;

  dim3 grid(B_TOTAL / NB);  // 256 blocks, 1 per CU
  dim3 block(BLOCK);
  hipLaunchKernelGGL(lstm2_persistent, grid, block, 0, stream,
                     input, Wih1, Whh1, bih1, bhh1, Wih2, Whh2, bih2, bhh2,
                     Wlin, blin, futp, out);
}

// Round 3
// 3396.579 us; speedup vs baseline: 5.8174x; 5.8174x over previous
//
#include <hip/hip_runtime.h>
#include <stdint.h>

// Problem constants
#define HID 100
#define GATES 400      // 4*H
#define B_TOTAL 512
#define T_IN 1000
#define NB 2           // batch elements per block
#define BLOCK 512
#define HPAD 112       // f16 h-vector padded stride (16B-aligned rows; 100..111 = 0)

// NOTE: the amdgcn builtins (__builtin_amdgcn_cvt_pkrtz / __builtin_amdgcn_fdot2)
// use the __fp16 vector type on this toolchain, NOT _Float16 (R2 compile error).
typedef __fp16 h2v __attribute__((ext_vector_type(2)));

__device__ __forceinline__ h2v as_h2(uint32_t u) {
  union { uint32_t i; h2v h; } v; v.i = u; return v.h;
}
__device__ __forceinline__ uint32_t pk(float a, float b) {
  // pack 2 fp32 -> f16x2 (RTZ). weights are ~0.1 scale; f16 has 11-bit mantissa.
  h2v h = __builtin_amdgcn_cvt_pkrtz(a, b);
  union { h2v h; uint32_t i; } u; u.h = h; return u.i;
}

#if __has_builtin(__builtin_amdgcn_fdot2)
#define FDOT2(w, h, c) __builtin_amdgcn_fdot2(as_h2(w), as_h2(h), (c), false)
#else
__device__ __forceinline__ float fdot2_fb(uint32_t a, uint32_t b, float c) {
  h2v x = as_h2(a), y = as_h2(b);
  return fmaf((float)x[1], (float)y[1], fmaf((float)x[0], (float)y[0], c));
}
#define FDOT2(w, h, c) fdot2_fb((w), (h), (c))
#endif

__device__ __forceinline__ float sigm(float x) { return 1.0f / (1.0f + __expf(-x)); }
__device__ __forceinline__ float tanh_fast(float x) {
  float e = __expf(2.0f * x);
  return 1.0f - 2.0f / (e + 1.0f);
}

// ---- repetition macros (all indices literal => SROA-safe named scalars) ----
#define REP13(M) M(0) M(1) M(2) M(3) M(4) M(5) M(6) M(7) M(8) M(9) M(10) M(11) M(12)
// groups q=0..11 map to float4 row indices (2q, 2q+1); group 12 is the 96..99 tail
#define REPW(M) M(0,0,1) M(1,2,3) M(2,4,5) M(3,6,7) M(4,8,9) M(5,10,11) \
                M(6,12,13) M(7,14,15) M(8,16,17) M(9,18,19) M(10,20,21) M(11,22,23)

// declare 156 named scalar weight regs: 13 groups x 4 u32 x 3 matrices
#define DECLW(q) uint32_t w1_##q##_0=0u,w1_##q##_1=0u,w1_##q##_2=0u,w1_##q##_3=0u, \
                          w2_##q##_0=0u,w2_##q##_1=0u,w2_##q##_2=0u,w2_##q##_3=0u, \
                          w3_##q##_0=0u,w3_##q##_1=0u,w3_##q##_2=0u,w3_##q##_3=0u;

#define LOADW(q,qa,qb) { float4 v; \
  v=r1[qa]; w1_##q##_0=pk(v.x,v.y); w1_##q##_1=pk(v.z,v.w); \
  v=r1[qb]; w1_##q##_2=pk(v.x,v.y); w1_##q##_3=pk(v.z,v.w); \
  v=r2[qa]; w2_##q##_0=pk(v.x,v.y); w2_##q##_1=pk(v.z,v.w); \
  v=r2[qb]; w2_##q##_2=pk(v.x,v.y); w2_##q##_3=pk(v.z,v.w); \
  v=r3[qa]; w3_##q##_0=pk(v.x,v.y); w3_##q##_1=pk(v.z,v.w); \
  v=r3[qb]; w3_##q##_2=pk(v.x,v.y); w3_##q##_3=pk(v.z,v.w); }

// gate inner groups: 1 uint4 LDS broadcast read per batch feeds 4 FDOT2 per batch
#define G1(q) { uint4 hv0=hA[q], hv1=hB[q]; \
  a0=FDOT2(w1_##q##_0,hv0.x,a0); a0=FDOT2(w1_##q##_1,hv0.y,a0); \
  a0=FDOT2(w1_##q##_2,hv0.z,a0); a0=FDOT2(w1_##q##_3,hv0.w,a0); \
  a1=FDOT2(w1_##q##_0,hv1.x,a1); a1=FDOT2(w1_##q##_1,hv1.y,a1); \
  a1=FDOT2(w1_##q##_2,hv1.z,a1); a1=FDOT2(w1_##q##_3,hv1.w,a1); }

#define G2(q) { uint4 hv0=hA[q], hv1=hB[q]; \
  a0=FDOT2(w2_##q##_0,hv0.x,a0); a0=FDOT2(w2_##q##_1,hv0.y,a0); \
  a0=FDOT2(w2_##q##_2,hv0.z,a0); a0=FDOT2(w2_##q##_3,hv0.w,a0); \
  a1=FDOT2(w2_##q##_0,hv1.x,a1); a1=FDOT2(w2_##q##_1,hv1.y,a1); \
  a1=FDOT2(w2_##q##_2,hv1.z,a1); a1=FDOT2(w2_##q##_3,hv1.w,a1); }

#define G3(q) { uint4 hv0=hC[q], hv1=hD[q]; \
  a0=FDOT2(w3_##q##_0,hv0.x,a0); a0=FDOT2(w3_##q##_1,hv0.y,a0); \
  a0=FDOT2(w3_##q##_2,hv0.z,a0); a0=FDOT2(w3_##q##_3,hv0.w,a0); \
  a1=FDOT2(w3_##q##_0,hv1.x,a1); a1=FDOT2(w3_##q##_1,hv1.y,a1); \
  a1=FDOT2(w3_##q##_2,hv1.z,a1); a1=FDOT2(w3_##q##_3,hv1.w,a1); }

#define GATES1_BODY(X0, X1) { \
  float a0 = fmaf((X0), wih1_j, b1j); \
  float a1 = fmaf((X1), wih1_j, b1j); \
  const uint4* hA = (const uint4*)h1h[0]; const uint4* hB = (const uint4*)h1h[1]; \
  REP13(G1) \
  gb[0][j] = a0; gb[1][j] = a1; }

#define GATES2_BODY { \
  float a0 = b2j, a1 = b2j; \
  const uint4* hA = (const uint4*)h1h[0]; const uint4* hB = (const uint4*)h1h[1]; \
  REP13(G2) \
  const uint4* hC = (const uint4*)h2h[0]; const uint4* hD = (const uint4*)h2h[1]; \
  REP13(G3) \
  gb[0][j] = a0; gb[1][j] = a1; }

#define ACT1_BODY { \
  float gi=gb[actb][actk], gf=gb[actb][actk+100], gg=gb[actb][actk+200], go=gb[actb][actk+300]; \
  c1 = sigm(gf)*c1 + sigm(gi)*tanh_fast(gg); \
  h1h[actb][actk] = (_Float16)(sigm(go)*tanh_fast(c1)); }

#define ACT2_BODY { \
  float gi=gb[actb][actk], gf=gb[actb][actk+100], gg=gb[actb][actk+200], go=gb[actb][actk+300]; \
  c2 = sigm(gf)*c2 + sigm(gi)*tanh_fast(gg); \
  float hv = sigm(go)*tanh_fast(c2); \
  h2h[actb][actk] = (_Float16)hv; h2s[actb][actk] = hv; }

// wave 7 (tids 448..511): y = h2 . wlin + blin for both batches, off critical path.
// lanes 0..31 -> batch 0, lanes 32..63 -> batch 1; reduce within 32-lane segments.
#define Y_BODY(tt) { \
  float s = h2s[ybat][yl]*wl0 + h2s[ybat][yl+32]*wl1 + h2s[ybat][yl+64]*wl2; \
  if (yl < 4) s = fmaf(h2s[ybat][yl+96], wl3, s); \
  s += __shfl_down(s, 16, 32); \
  s += __shfl_down(s, 8, 32); \
  s += __shfl_down(s, 4, 32); \
  s += __shfl_down(s, 2, 32); \
  s += __shfl_down(s, 1, 32); \
  if (yl == 0) { float y = s + blin0; yb[ybat] = y; \
    out[(size_t)(b0 + ybat) * TT + (tt)] = y; } }

__global__ __launch_bounds__(BLOCK, 2) void lstm2_persistent(
    const float* __restrict__ input,  // [512,1000]
    const float* __restrict__ Wih1,   // [400,1]
    const float* __restrict__ Whh1,   // [400,100]
    const float* __restrict__ bih1,
    const float* __restrict__ bhh1,
    const float* __restrict__ Wih2,   // [400,100]
    const float* __restrict__ Whh2,   // [400,100]
    const float* __restrict__ bih2,
    const float* __restrict__ bhh2,
    const float* __restrict__ Wlin,   // [1,100]
    const float* __restrict__ blin,   // [1]
    const int* __restrict__ futp,     // scalar
    float* __restrict__ out)          // [512, 1000+future]
{
  __shared__ float xrow[NB][T_IN];                    // staged input rows (8 KB)
  __shared__ __align__(16) _Float16 h1h[NB][HPAD];    // h1 as f16 (448 B)
  __shared__ __align__(16) _Float16 h2h[NB][HPAD];    // h2 as f16
  __shared__ float h2s[NB][HID];                      // h2 fp32 copy for y-dot
  __shared__ float gb[NB][GATES];                     // gate pre-activations (3.2 KB)
  __shared__ float yb[NB];                            // y feedback

  const int tid = threadIdx.x;
  const int b0 = blockIdx.x * NB;
  const int F = futp[0];
  const int TT = T_IN + F;

  // stage input rows
  for (int i = tid; i < NB * T_IN; i += BLOCK) {
    int b = i / T_IN, t = i % T_IN;
    xrow[b][t] = input[(size_t)(b0 + b) * T_IN + t];
  }
  // zero f16 h buffers (incl. pads — pads stay 0 forever)
  if (tid < NB * HPAD / 2) {
    ((uint32_t*)h1h)[tid] = 0u;
    ((uint32_t*)h2h)[tid] = 0u;
  }

  // ---- register-stationary weights: 156 NAMED scalars (no array => no scratch) ----
  REP13(DECLW)
  const int j = tid;
  float wih1_j = 0.0f, b1j = 0.0f, b2j = 0.0f;
  if (j < GATES) {
    wih1_j = Wih1[j];
    b1j = bih1[j] + bhh1[j];
    b2j = bih2[j] + bhh2[j];
    const float4* r1 = (const float4*)(Whh1 + j * HID);
    const float4* r2 = (const float4*)(Wih2 + j * HID);
    const float4* r3 = (const float4*)(Whh2 + j * HID);
    REPW(LOADW)
    { float4 v = r1[24]; w1_12_0 = pk(v.x, v.y); w1_12_1 = pk(v.z, v.w); }
    { float4 v = r2[24]; w2_12_0 = pk(v.x, v.y); w2_12_1 = pk(v.z, v.w); }
    { float4 v = r3[24]; w3_12_0 = pk(v.x, v.y); w3_12_1 = pk(v.z, v.w); }
    // w*_12_2 / w*_12_3 stay 0 (pad)
  }

  // activation roles: (b=0,k)=tids 0..99 ; (b=1,k)=tids 256..355
  int actb = -1, actk = 0;
  if (tid < HID) { actb = 0; actk = tid; }
  else if (tid >= 256 && tid < 256 + HID) { actb = 1; actk = tid - 256; }
  float c1 = 0.0f, c2 = 0.0f;

  // wave-7 y-duty registers
  float wl0 = 0.f, wl1 = 0.f, wl2 = 0.f, wl3 = 0.f;
  int yl = 0, ybat = 0;
  if (tid >= 448) {
    int lane = tid - 448;
    ybat = lane >> 5; yl = lane & 31;
    wl0 = Wlin[yl]; wl1 = Wlin[yl + 32]; wl2 = Wlin[yl + 64];
    wl3 = (yl < 4) ? Wlin[yl + 96] : 0.0f;
  }
  const float blin0 = blin[0];

  // ================= phase 1: teacher-forced, 4 barriers/step =================
  // y_{t-1} is computed by wave 7 concurrently with gates1 of step t.
  for (int t = 0; t < T_IN; t++) {
    __syncthreads();  // A: h2s/h2h of t-1 ready; gb free; (t=0: staging visible)
    if (j < GATES) { float x0 = xrow[0][t], x1 = xrow[1][t]; GATES1_BODY(x0, x1) }
    if (tid >= 448 && t > 0) { Y_BODY(t - 1) }
    __syncthreads();  // B: gb ready
    if (actb >= 0) ACT1_BODY
    __syncthreads();  // C: h1h ready
    if (j < GATES) GATES2_BODY
    __syncthreads();  // D: gb ready
    if (actb >= 0) ACT2_BODY
  }
  __syncthreads();
  if (tid >= 448) { Y_BODY(T_IN - 1) }  // y_999 -> out and yb
  __syncthreads();

  // ================= phase 2: autoregressive, 5 barriers/step =================
  for (int t = T_IN; t < TT; t++) {
    if (j < GATES) { float x0 = yb[0], x1 = yb[1]; GATES1_BODY(x0, x1) }
    __syncthreads();  // B
    if (actb >= 0) ACT1_BODY
    __syncthreads();  // C
    if (j < GATES) GATES2_BODY
    __syncthreads();  // D
    if (actb >= 0) ACT2_BODY
    __syncthreads();  // E: h2s ready
    if (tid >= 448) { Y_BODY(t) }
    __syncthreads();  // A-next: yb visible, gb free
  }
}

extern "C" void kernel_launch(void* const* d_in, const int* in_sizes, int n_in,
                              void* d_out, int out_size, void* d_ws, size_t ws_size,
                              hipStream_t stream) {
  const float* input = (const float*)d_in[0];
  const float* Wih1  = (const float*)d_in[1];
  const float* Whh1  = (const float*)d_in[2];
  const float* bih1  = (const float*)d_in[3];
  const float* bhh1  = (const float*)d_in[4];
  const float* Wih2  = (const float*)d_in[5];
  const float* Whh2  = (const float*)d_in[6];
  const float* bih2  = (const float*)d_in[7];
  const float* bhh2  = (const float*)d_in[8];
  const float* Wlin  = (const float*)d_in[9];
  const float* blin  = (const float*)d_in[10];
  const int*   futp  = (const int*)d_in[11];
  float* out = (float*)d_out;

  dim3 grid(B_TOTAL / NB);  // 256 blocks, 1 per CU
  dim3 block(BLOCK);
  hipLaunchKernelGGL(lstm2_persistent, grid, block, 0, stream,
                     input, Wih1, Whh1, bih1, bhh1, Wih2, Whh2, bih2, bhh2,
                     Wlin, blin, futp, out);
}

// Round 4
// 3250.576 us; speedup vs baseline: 6.0787x; 1.0449x over previous
//
#include <hip/hip_runtime.h>
#include <stdint.h>

// Problem constants
#define HID 100
#define GATES 400      // 4*H
#define B_TOTAL 512
#define T_IN 1000
#define NB 2           // batch elements per block
#define BLOCK 1024
#define HPADH 112      // f16 h-vector padded length (56 u32; pads stay 0)

// amdgcn builtins use __fp16 vectors on this toolchain (R2 compile error w/ _Float16)
typedef __fp16 h2v __attribute__((ext_vector_type(2)));

__device__ __forceinline__ h2v as_h2(uint32_t u) {
  union { uint32_t i; h2v h; } v; v.i = u; return v.h;
}
__device__ __forceinline__ uint32_t pk(float a, float b) {
  h2v h = __builtin_amdgcn_cvt_pkrtz(a, b);
  union { h2v h; uint32_t i; } u; u.h = h; return u.i;
}

#if __has_builtin(__builtin_amdgcn_fdot2)
#define FDOT2(w, h, c) __builtin_amdgcn_fdot2(as_h2(w), as_h2(h), (c), false)
#else
__device__ __forceinline__ float fdot2_fb(uint32_t a, uint32_t b, float c) {
  h2v x = as_h2(a), y = as_h2(b);
  return fmaf((float)x[1], (float)y[1], fmaf((float)x[0], (float)y[0], c));
}
#define FDOT2(w, h, c) fdot2_fb((w), (h), (c))
#endif

__device__ __forceinline__ float sigm(float x) { return 1.0f / (1.0f + __expf(-x)); }
__device__ __forceinline__ float tanh_fast(float x) {
  float e = __expf(2.0f * x);
  return 1.0f - 2.0f / (e + 1.0f);
}

// ---- per-matrix weight registers: 28 named u32 (slots s <-> elems 48h+2s,48h+2s+1)
// h=0: slots 0..23 valid (elems 0..47), 24..27 zero.
// h=1: slots 0..25 valid (elems 48..99), 26..27 zero.
#define DECLW(P) uint32_t P##_0=0u,P##_1=0u,P##_2=0u,P##_3=0u,P##_4=0u,P##_5=0u, \
  P##_6=0u,P##_7=0u,P##_8=0u,P##_9=0u,P##_10=0u,P##_11=0u,P##_12=0u,P##_13=0u, \
  P##_14=0u,P##_15=0u,P##_16=0u,P##_17=0u,P##_18=0u,P##_19=0u,P##_20=0u,P##_21=0u, \
  P##_22=0u,P##_23=0u,P##_24=0u,P##_25=0u,P##_26=0u,P##_27=0u;

#define LDW(P, r) { float4 v; \
  v=(r)[qb+0];  P##_0 =pk(v.x,v.y); P##_1 =pk(v.z,v.w); \
  v=(r)[qb+1];  P##_2 =pk(v.x,v.y); P##_3 =pk(v.z,v.w); \
  v=(r)[qb+2];  P##_4 =pk(v.x,v.y); P##_5 =pk(v.z,v.w); \
  v=(r)[qb+3];  P##_6 =pk(v.x,v.y); P##_7 =pk(v.z,v.w); \
  v=(r)[qb+4];  P##_8 =pk(v.x,v.y); P##_9 =pk(v.z,v.w); \
  v=(r)[qb+5];  P##_10=pk(v.x,v.y); P##_11=pk(v.z,v.w); \
  v=(r)[qb+6];  P##_12=pk(v.x,v.y); P##_13=pk(v.z,v.w); \
  v=(r)[qb+7];  P##_14=pk(v.x,v.y); P##_15=pk(v.z,v.w); \
  v=(r)[qb+8];  P##_16=pk(v.x,v.y); P##_17=pk(v.z,v.w); \
  v=(r)[qb+9];  P##_18=pk(v.x,v.y); P##_19=pk(v.z,v.w); \
  v=(r)[qb+10]; P##_20=pk(v.x,v.y); P##_21=pk(v.z,v.w); \
  v=(r)[qb+11]; P##_22=pk(v.x,v.y); P##_23=pk(v.z,v.w); \
  if (hh) { v=(r)[24]; P##_24=pk(v.x,v.y); P##_25=pk(v.z,v.w); } }

// dot both batches: U/V = uint4* streams (batch0/1) at u32 base 24*hh; A0/A1 accums
#define DG(P,g,s0,s1,s2,s3,U,V,A0,A1) { uint4 u=(U)[g], w_=(V)[g]; \
  A0=FDOT2(P##_##s0,u.x,A0);  A0=FDOT2(P##_##s1,u.y,A0); \
  A0=FDOT2(P##_##s2,u.z,A0);  A0=FDOT2(P##_##s3,u.w,A0); \
  A1=FDOT2(P##_##s0,w_.x,A1); A1=FDOT2(P##_##s1,w_.y,A1); \
  A1=FDOT2(P##_##s2,w_.z,A1); A1=FDOT2(P##_##s3,w_.w,A1); }

#define DOT2(P,U,V,A0,A1) \
  DG(P,0,0,1,2,3,U,V,A0,A1)     DG(P,1,4,5,6,7,U,V,A0,A1) \
  DG(P,2,8,9,10,11,U,V,A0,A1)   DG(P,3,12,13,14,15,U,V,A0,A1) \
  DG(P,4,16,17,18,19,U,V,A0,A1) DG(P,5,20,21,22,23,U,V,A0,A1) \
  DG(P,6,24,25,26,27,U,V,A0,A1)

__global__ __launch_bounds__(BLOCK, 4) void lstm2_persistent(
    const float* __restrict__ input,  // [512,1000]
    const float* __restrict__ Wih1,   // [400,1]
    const float* __restrict__ Whh1,   // [400,100]
    const float* __restrict__ bih1,
    const float* __restrict__ bhh1,
    const float* __restrict__ Wih2,   // [400,100]
    const float* __restrict__ Whh2,   // [400,100]
    const float* __restrict__ bih2,
    const float* __restrict__ bhh2,
    const float* __restrict__ Wlin,   // [1,100]
    const float* __restrict__ blin,   // [1]
    const int* __restrict__ futp,     // scalar
    float* __restrict__ out)          // [512, 1000+future]
{
  __shared__ float xrow[NB][T_IN];                   // 8 KB staged inputs
  __shared__ __align__(16) _Float16 h1h[NB][HPADH];  // h1 f16 (448 B)
  __shared__ __align__(16) _Float16 h2h[NB][HPADH];  // h2 f16
  __shared__ float h2s[NB][104];                     // h2 fp32 (for y), pads 0
  __shared__ float gb[NB][GATES];                    // gate pre-activations
  __shared__ float wls[104];                         // Wlin staged, pads 0
  __shared__ float ybf[NB];                          // y feedback

  const int tid = threadIdx.x;
  const int b0 = blockIdx.x * NB;
  const int F = futp[0];
  const int TT = T_IN + F;

  // stage inputs
  for (int i = tid; i < NB * T_IN; i += BLOCK) {
    int b = i / T_IN, t = i % T_IN;
    xrow[b][t] = input[(size_t)(b0 + b) * T_IN + t];
  }
  // zero h buffers (incl pads)
  if (tid < NB * HPADH / 2) {
    ((uint32_t*)h1h)[tid] = 0u;
    ((uint32_t*)h2h)[tid] = 0u;
  }
  if (tid < NB * 104) ((float*)h2s)[tid] = 0.0f;
  if (tid < 104) wls[tid] = (tid < HID) ? Wlin[tid] : 0.0f;

  // ---- gate duty: tid 0..799, row j = tid>>1, K-half hh = tid&1 ----
  const int is_gate = (tid < 2 * GATES);
  const int j = tid >> 1;
  const int hh = tid & 1;
  const int qb = 12 * hh;  // first float4 of this half-row

  DECLW(W1) DECLW(W2) DECLW(W3)
  float wih1_j = 0.0f, b1j = 0.0f, b2j = 0.0f;
  if (is_gate) {
    if (hh == 0) {  // bias/x-term only on the h=0 lane (pair-sum would double it)
      wih1_j = Wih1[j];
      b1j = bih1[j] + bhh1[j];
      b2j = bih2[j] + bhh2[j];
    }
    const float4* r1 = (const float4*)(Whh1 + j * HID);
    const float4* r2 = (const float4*)(Wih2 + j * HID);
    const float4* r3 = (const float4*)(Whh2 + j * HID);
    LDW(W1, r1) LDW(W2, r2) LDW(W3, r3)
  }
  // h-stream bases (u32 index 24*hh -> byte 96*hh, 16B aligned)
  const uint4* hA = (const uint4*)((const uint32_t*)h1h[0] + 24 * hh);
  const uint4* hB = (const uint4*)((const uint32_t*)h1h[1] + 24 * hh);
  const uint4* hC = (const uint4*)((const uint32_t*)h2h[0] + 24 * hh);
  const uint4* hD = (const uint4*)((const uint32_t*)h2h[1] + 24 * hh);

  // ---- act duty: tid 800..999 -> (batch ab, cell ak) ----
  const int aidx = tid - 2 * GATES;
  const int is_act = (aidx >= 0 && aidx < NB * HID);
  const int ab = (aidx >= HID) ? 1 : 0;
  const int ak = aidx - HID * ab;
  float c1 = 0.0f, c2 = 0.0f;

  // ---- y duty: tid 1008..1023 (wave-15 lanes 48..63) ----
  const int is_y = (tid >= 1008);
  const int yi = tid - 1008;
  const int ybat = (yi >> 3) & 1;
  const int yl = yi & 7;
  const float blin0 = blin[0];

#define P0_BODY(X0, X1) { \
    float a0 = b1j, a1 = b1j; \
    a0 = fmaf((X0), wih1_j, a0); a1 = fmaf((X1), wih1_j, a1); \
    DOT2(W1, hA, hB, a0, a1) \
    a0 += __shfl_xor(a0, 1); a1 += __shfl_xor(a1, 1); \
    if (hh == 0) gb[0][j] = a0; else gb[1][j] = a1; \
    p0 = b2j; p1 = b2j; \
    DOT2(W3, hC, hD, p0, p1) }

#define P2_BODY { \
    DOT2(W2, hA, hB, p0, p1) \
    p0 += __shfl_xor(p0, 1); p1 += __shfl_xor(p1, 1); \
    if (hh == 0) gb[0][j] = p0; else gb[1][j] = p1; }

#define ACT1_BODY { \
    float gi = gb[ab][ak], gf = gb[ab][ak+100], gg = gb[ab][ak+200], go = gb[ab][ak+300]; \
    c1 = sigm(gf)*c1 + sigm(gi)*tanh_fast(gg); \
    h1h[ab][ak] = (_Float16)(sigm(go)*tanh_fast(c1)); }

#define ACT2_BODY { \
    float gi = gb[ab][ak], gf = gb[ab][ak+100], gg = gb[ab][ak+200], go = gb[ab][ak+300]; \
    c2 = sigm(gf)*c2 + sigm(gi)*tanh_fast(gg); \
    float hv = sigm(go)*tanh_fast(c2); \
    h2h[ab][ak] = (_Float16)hv; h2s[ab][ak] = hv; }

#define Y_BODY(tt) { \
    float s = 0.0f; \
    _Pragma("unroll") \
    for (int m = 0; m < 13; m++) s = fmaf(h2s[ybat][yl + 8*m], wls[yl + 8*m], s); \
    s += __shfl_down(s, 4, 8); \
    s += __shfl_down(s, 2, 8); \
    s += __shfl_down(s, 1, 8); \
    if (yl == 0) { float y = s + blin0; ybf[ybat] = y; \
      out[(size_t)(b0 + ybat) * TT + (tt)] = y; } }

  // ================= phase 1: teacher-forced, 4 barriers/step =================
  for (int t = 0; t < T_IN; t++) {
    __syncthreads();  // A: prev-step h1h/h2h/h2s visible; gb free
    float p0 = 0.f, p1 = 0.f;
    if (is_gate) { float x0 = xrow[0][t], x1 = xrow[1][t]; P0_BODY(x0, x1) }
    if (is_y && t > 0) Y_BODY(t - 1)   // y(t-1) off the critical path
    __syncthreads();  // B: gb (gates1) ready
    if (is_act) ACT1_BODY
    __syncthreads();  // C: h1h(t) ready
    if (is_gate) P2_BODY
    __syncthreads();  // D: gb (gates2) ready
    if (is_act) ACT2_BODY
  }
  __syncthreads();
  if (is_y) Y_BODY(T_IN - 1)
  __syncthreads();

  // ================= phase 2: autoregressive, 5 barriers/step =================
  for (int t = T_IN; t < TT; t++) {
    float p0 = 0.f, p1 = 0.f;
    if (is_gate) { float x0 = ybf[0], x1 = ybf[1]; P0_BODY(x0, x1) }
    __syncthreads();  // B
    if (is_act) ACT1_BODY
    __syncthreads();  // C
    if (is_gate) P2_BODY
    __syncthreads();  // D
    if (is_act) ACT2_BODY
    __syncthreads();  // E: h2s ready
    if (is_y) Y_BODY(t)
    __syncthreads();  // A-next: ybf visible, gb free
  }
}

extern "C" void kernel_launch(void* const* d_in, const int* in_sizes, int n_in,
                              void* d_out, int out_size, void* d_ws, size_t ws_size,
                              hipStream_t stream) {
  const float* input = (const float*)d_in[0];
  const float* Wih1  = (const float*)d_in[1];
  const float* Whh1  = (const float*)d_in[2];
  const float* bih1  = (const float*)d_in[3];
  const float* bhh1  = (const float*)d_in[4];
  const float* Wih2  = (const float*)d_in[5];
  const float* Whh2  = (const float*)d_in[6];
  const float* bih2  = (const float*)d_in[7];
  const float* bhh2  = (const float*)d_in[8];
  const float* Wlin  = (const float*)d_in[9];
  const float* blin  = (const float*)d_in[10];
  const int*   futp  = (const int*)d_in[11];
  float* out = (float*)d_out;

  dim3 grid(B_TOTAL / NB);  // 256 blocks, 1 per CU
  dim3 block(BLOCK);
  hipLaunchKernelGGL(lstm2_persistent, grid, block, 0, stream,
                     input, Wih1, Whh1, bih1, bhh1, Wih2, Whh2, bih2, bhh2,
                     Wlin, blin, futp, out);
}

// Round 5
// 2039.596 us; speedup vs baseline: 9.6878x; 1.5937x over previous
//
#include <hip/hip_runtime.h>
#include <stdint.h>

// Problem constants
#define HID 100
#define B_TOTAL 512
#define T_IN 1000
#define NB 2
#define BLOCK 512   // 8 waves -> 2 waves/EU -> 256-VGPR cap

// amdgcn builtins use __fp16 vectors on this toolchain (R2 evidence)
typedef __fp16 f16x8 __attribute__((ext_vector_type(8)));
typedef float f32x4 __attribute__((ext_vector_type(4)));

#define MF(A, B, C) __builtin_amdgcn_mfma_f32_16x16x32_f16((A), (B), (C), 0, 0, 0)

__device__ __forceinline__ float sigm(float x) { return 1.0f / (1.0f + __expf(-x)); }
__device__ __forceinline__ float tanh_fast(float x) {
  float e = __expf(2.0f * x);
  return 1.0f - 2.0f / (e + 1.0f);
}

// A-fragment LDS index for element (k, m): tile k>>5, lane ((k&31)>>3)*16+m, elem k&7
__device__ __forceinline__ int aidx(int k, int m) {
  return (k >> 5) * 512 + (((k & 31) >> 3) * 16 + m) * 8 + (k & 7);
}

// weight element fetchers (return f16; 0 in pad regions)
__device__ __forceinline__ __fp16 w1e(const float* Whh1, const float* Wih1, int j, int k) {
  float v = 0.0f;
  if (k < 100) v = Whh1[j * 100 + k];
  else if (k == 100) v = Wih1[j];
  return (__fp16)v;
}
__device__ __forceinline__ __fp16 w2e(const float* Wih2, const float* Whh2, int j, int k) {
  float v = 0.0f;
  if (k < 100) v = Wih2[j * 100 + k];
  else if (k >= 112 && k < 212) v = Whh2[j * 100 + (k - 112)];
  return (__fp16)v;
}

// B-fragment literal builders: element j of frag = B[k = KT*32 + kg*8 + j][n = J's row]
#define MKB1(J, KT) (f16x8){ \
  w1e(Whh1, Wih1, (J), (KT)*32 + kg*8 + 0), w1e(Whh1, Wih1, (J), (KT)*32 + kg*8 + 1), \
  w1e(Whh1, Wih1, (J), (KT)*32 + kg*8 + 2), w1e(Whh1, Wih1, (J), (KT)*32 + kg*8 + 3), \
  w1e(Whh1, Wih1, (J), (KT)*32 + kg*8 + 4), w1e(Whh1, Wih1, (J), (KT)*32 + kg*8 + 5), \
  w1e(Whh1, Wih1, (J), (KT)*32 + kg*8 + 6), w1e(Whh1, Wih1, (J), (KT)*32 + kg*8 + 7) }
#define MKB2(J, KT) (f16x8){ \
  w2e(Wih2, Whh2, (J), (KT)*32 + kg*8 + 0), w2e(Wih2, Whh2, (J), (KT)*32 + kg*8 + 1), \
  w2e(Wih2, Whh2, (J), (KT)*32 + kg*8 + 2), w2e(Wih2, Whh2, (J), (KT)*32 + kg*8 + 3), \
  w2e(Wih2, Whh2, (J), (KT)*32 + kg*8 + 4), w2e(Wih2, Whh2, (J), (KT)*32 + kg*8 + 5), \
  w2e(Wih2, Whh2, (J), (KT)*32 + kg*8 + 6), w2e(Wih2, Whh2, (J), (KT)*32 + kg*8 + 7) }

__global__ __launch_bounds__(BLOCK, 2) void lstm2_mfma(
    const float* __restrict__ input,  // [512,1000]
    const float* __restrict__ Wih1,   // [400,1]
    const float* __restrict__ Whh1,   // [400,100]
    const float* __restrict__ bih1,
    const float* __restrict__ bhh1,
    const float* __restrict__ Wih2,   // [400,100]
    const float* __restrict__ Whh2,   // [400,100]
    const float* __restrict__ bih2,
    const float* __restrict__ bhh2,
    const float* __restrict__ Wlin,   // [1,100]
    const float* __restrict__ blin,   // [1]
    const int* __restrict__ futp,
    float* __restrict__ out)          // [512, 1000+future]
{
  // A operands in MFMA A-fragment order (rows m>=2 stay zero forever)
  __shared__ __align__(16) __fp16 A1h[4 * 512];   // L1: k0..99=h1(t-1), k100=x(t), rest 0
  __shared__ __align__(16) __fp16 A2h[7 * 512];   // L2: k0..99=h1(t), k112..211=h2(t-1)
  // B fragments for N-tile 24 (gates 384..399) — LDS-resident, wave 0 reads per step
  __shared__ __align__(16) __fp16 BL1h[4 * 512];
  __shared__ __align__(16) __fp16 BL2h[7 * 512];
  __shared__ float2 gb2[400];        // gate pre-acts: [n](batch0, batch1)
  __shared__ float xrow[NB][T_IN];   // staged inputs (8 KB)
  __shared__ float ybuf[NB][104];    // h2(t) f32 for y-dot (pads 0)
  __shared__ float wls[104];         // Wlin staged (pads 0)

  const int tid = threadIdx.x;
  const int lane = tid & 63;
  const int wv = tid >> 6;
  const int b0 = blockIdx.x * NB;
  const int F = futp[0];
  const int TT = T_IN + F;

  // ---------------- init: stage + zero ----------------
  for (int i = tid; i < NB * T_IN; i += BLOCK) {
    int b = i / T_IN, t = i % T_IN;
    xrow[b][t] = input[(size_t)(b0 + b) * T_IN + t];
  }
  for (int i = tid; i < 1024; i += BLOCK) ((uint32_t*)A1h)[i] = 0u;
  for (int i = tid; i < 1792; i += BLOCK) ((uint32_t*)A2h)[i] = 0u;
  if (tid < 104) { wls[tid] = (tid < HID) ? Wlin[tid] : 0.0f; }
  if (tid < 208) { ((float*)ybuf)[tid] = 0.0f; }

  // ---------------- register-resident B fragments ----------------
  const int n15 = lane & 15;
  const int kg = (lane >> 4) & 3;
  const int j0 = (wv) * 16 + n15;        // N-tile wv
  const int j1 = (8 + wv) * 16 + n15;    // N-tile 8+wv
  const int j2 = (16 + wv) * 16 + n15;   // N-tile 16+wv
  f16x8 B1_0_0 = MKB1(j0, 0), B1_0_1 = MKB1(j0, 1), B1_0_2 = MKB1(j0, 2), B1_0_3 = MKB1(j0, 3);
  f16x8 B1_1_0 = MKB1(j1, 0), B1_1_1 = MKB1(j1, 1), B1_1_2 = MKB1(j1, 2), B1_1_3 = MKB1(j1, 3);
  f16x8 B1_2_0 = MKB1(j2, 0), B1_2_1 = MKB1(j2, 1), B1_2_2 = MKB1(j2, 2), B1_2_3 = MKB1(j2, 3);
  f16x8 B2_0_0 = MKB2(j0, 0), B2_0_1 = MKB2(j0, 1), B2_0_2 = MKB2(j0, 2), B2_0_3 = MKB2(j0, 3),
        B2_0_4 = MKB2(j0, 4), B2_0_5 = MKB2(j0, 5), B2_0_6 = MKB2(j0, 6);
  f16x8 B2_1_0 = MKB2(j1, 0), B2_1_1 = MKB2(j1, 1), B2_1_2 = MKB2(j1, 2), B2_1_3 = MKB2(j1, 3),
        B2_1_4 = MKB2(j1, 4), B2_1_5 = MKB2(j1, 5), B2_1_6 = MKB2(j1, 6);
  f16x8 B2_2_0 = MKB2(j2, 0), B2_2_1 = MKB2(j2, 1), B2_2_2 = MKB2(j2, 2), B2_2_3 = MKB2(j2, 3),
        B2_2_4 = MKB2(j2, 4), B2_2_5 = MKB2(j2, 5), B2_2_6 = MKB2(j2, 6);

  // N-tile 24 fragments -> LDS (tids 0..63 emulate one wave's lanes)
  if (tid < 64) {
    int jj = 384 + n15;  // kg is this tid's kg — same mapping as a reading lane
    f16x8* BV1 = (f16x8*)BL1h;
    f16x8* BV2 = (f16x8*)BL2h;
    BV1[0 * 64 + tid] = MKB1(jj, 0); BV1[1 * 64 + tid] = MKB1(jj, 1);
    BV1[2 * 64 + tid] = MKB1(jj, 2); BV1[3 * 64 + tid] = MKB1(jj, 3);
    BV2[0 * 64 + tid] = MKB2(jj, 0); BV2[1 * 64 + tid] = MKB2(jj, 1);
    BV2[2 * 64 + tid] = MKB2(jj, 2); BV2[3 * 64 + tid] = MKB2(jj, 3);
    BV2[4 * 64 + tid] = MKB2(jj, 4); BV2[5 * 64 + tid] = MKB2(jj, 5);
    BV2[6 * 64 + tid] = MKB2(jj, 6);
  }

  // ---------------- act duty: tids 256..455 -> (b, k) ----------------
  const int is_act = (tid >= 256 && tid < 256 + NB * HID);
  const int ab = (tid - 256) & 1;
  const int ak = (tid - 256) >> 1;
  float b1i = 0, b1f = 0, b1g = 0, b1o = 0, b2i = 0, b2f = 0, b2g = 0, b2o = 0;
  if (is_act) {
    b1i = bih1[ak] + bhh1[ak];           b1f = bih1[ak + 100] + bhh1[ak + 100];
    b1g = bih1[ak + 200] + bhh1[ak + 200]; b1o = bih1[ak + 300] + bhh1[ak + 300];
    b2i = bih2[ak] + bhh2[ak];           b2f = bih2[ak + 100] + bhh2[ak + 100];
    b2g = bih2[ak + 200] + bhh2[ak + 200]; b2o = bih2[ak + 300] + bhh2[ak + 300];
  }
  float c1v = 0.0f, c2v = 0.0f;

  // ---------------- y duty: tids 496..511 ----------------
  const int is_y = (tid >= 496);
  const int ybat = ((tid - 496) >> 3) & 1;
  const int yl = (tid - 496) & 7;
  const float blin0 = blin[0];

  __syncthreads();
  // x(0) into A1 (after zeroing barrier)
  if (tid >= 464 && tid < 466) A1h[aidx(100, tid - 464)] = (__fp16)xrow[tid - 464][0];

#define L1_PHASE { \
    const f16x8* A1v = (const f16x8*)A1h; \
    f16x8 a0 = A1v[lane], a1 = A1v[64 + lane], a2 = A1v[128 + lane], a3 = A1v[192 + lane]; \
    f32x4 c0 = {0.f, 0.f, 0.f, 0.f}, c1 = {0.f, 0.f, 0.f, 0.f}, c2 = {0.f, 0.f, 0.f, 0.f}; \
    c0 = MF(a0, B1_0_0, c0); c0 = MF(a1, B1_0_1, c0); c0 = MF(a2, B1_0_2, c0); c0 = MF(a3, B1_0_3, c0); \
    c1 = MF(a0, B1_1_0, c1); c1 = MF(a1, B1_1_1, c1); c1 = MF(a2, B1_1_2, c1); c1 = MF(a3, B1_1_3, c1); \
    c2 = MF(a0, B1_2_0, c2); c2 = MF(a1, B1_2_1, c2); c2 = MF(a2, B1_2_2, c2); c2 = MF(a3, B1_2_3, c2); \
    if (wv == 0) { \
      const f16x8* Bv = (const f16x8*)BL1h; \
      f32x4 c3 = {0.f, 0.f, 0.f, 0.f}; \
      c3 = MF(a0, Bv[lane], c3); c3 = MF(a1, Bv[64 + lane], c3); \
      c3 = MF(a2, Bv[128 + lane], c3); c3 = MF(a3, Bv[192 + lane], c3); \
      if (lane < 16) gb2[384 + lane] = float2{c3[0], c3[1]}; \
    } \
    if (lane < 16) { \
      gb2[(wv << 4) + lane] = float2{c0[0], c0[1]}; \
      gb2[((8 + wv) << 4) + lane] = float2{c1[0], c1[1]}; \
      gb2[((16 + wv) << 4) + lane] = float2{c2[0], c2[1]}; \
    } }

#define L2_PHASE { \
    const f16x8* A2v = (const f16x8*)A2h; \
    f16x8 a0 = A2v[lane], a1 = A2v[64 + lane], a2 = A2v[128 + lane], a3 = A2v[192 + lane], \
          a4 = A2v[256 + lane], a5 = A2v[320 + lane], a6 = A2v[384 + lane]; \
    f32x4 c0 = {0.f, 0.f, 0.f, 0.f}, c1 = {0.f, 0.f, 0.f, 0.f}, c2 = {0.f, 0.f, 0.f, 0.f}; \
    c0 = MF(a0, B2_0_0, c0); c0 = MF(a1, B2_0_1, c0); c0 = MF(a2, B2_0_2, c0); c0 = MF(a3, B2_0_3, c0); \
    c0 = MF(a4, B2_0_4, c0); c0 = MF(a5, B2_0_5, c0); c0 = MF(a6, B2_0_6, c0); \
    c1 = MF(a0, B2_1_0, c1); c1 = MF(a1, B2_1_1, c1); c1 = MF(a2, B2_1_2, c1); c1 = MF(a3, B2_1_3, c1); \
    c1 = MF(a4, B2_1_4, c1); c1 = MF(a5, B2_1_5, c1); c1 = MF(a6, B2_1_6, c1); \
    c2 = MF(a0, B2_2_0, c2); c2 = MF(a1, B2_2_1, c2); c2 = MF(a2, B2_2_2, c2); c2 = MF(a3, B2_2_3, c2); \
    c2 = MF(a4, B2_2_4, c2); c2 = MF(a5, B2_2_5, c2); c2 = MF(a6, B2_2_6, c2); \
    if (wv == 0) { \
      const f16x8* Bv = (const f16x8*)BL2h; \
      f32x4 c3 = {0.f, 0.f, 0.f, 0.f}; \
      c3 = MF(a0, Bv[lane], c3); c3 = MF(a1, Bv[64 + lane], c3); c3 = MF(a2, Bv[128 + lane], c3); \
      c3 = MF(a3, Bv[192 + lane], c3); c3 = MF(a4, Bv[256 + lane], c3); c3 = MF(a5, Bv[320 + lane], c3); \
      c3 = MF(a6, Bv[384 + lane], c3); \
      if (lane < 16) gb2[384 + lane] = float2{c3[0], c3[1]}; \
    } \
    if (lane < 16) { \
      gb2[(wv << 4) + lane] = float2{c0[0], c0[1]}; \
      gb2[((8 + wv) << 4) + lane] = float2{c1[0], c1[1]}; \
      gb2[((16 + wv) << 4) + lane] = float2{c2[0], c2[1]}; \
    } }

#define ACT1_BODY { \
    const float* gbf = (const float*)gb2; \
    float gi = gbf[(ak) * 2 + ab] + b1i; \
    float gf = gbf[(ak + 100) * 2 + ab] + b1f; \
    float gg = gbf[(ak + 200) * 2 + ab] + b1g; \
    float go = gbf[(ak + 300) * 2 + ab] + b1o; \
    c1v = sigm(gf) * c1v + sigm(gi) * tanh_fast(gg); \
    __fp16 h = (__fp16)(sigm(go) * tanh_fast(c1v)); \
    A1h[aidx(ak, ab)] = h; A2h[aidx(ak, ab)] = h; }

#define ACT2_BODY { \
    const float* gbf = (const float*)gb2; \
    float gi = gbf[(ak) * 2 + ab] + b2i; \
    float gf = gbf[(ak + 100) * 2 + ab] + b2f; \
    float gg = gbf[(ak + 200) * 2 + ab] + b2g; \
    float go = gbf[(ak + 300) * 2 + ab] + b2o; \
    c2v = sigm(gf) * c2v + sigm(gi) * tanh_fast(gg); \
    float hv = sigm(go) * tanh_fast(c2v); \
    A2h[aidx(112 + ak, ab)] = (__fp16)hv; ybuf[ab][ak] = hv; }

#define Y_BODY(tt, FEED) { \
    float s = 0.0f; \
    _Pragma("unroll") \
    for (int m = 0; m < 13; m++) s = fmaf(ybuf[ybat][yl + 8 * m], wls[yl + 8 * m], s); \
    s += __shfl_down(s, 4, 8); \
    s += __shfl_down(s, 2, 8); \
    s += __shfl_down(s, 1, 8); \
    if (yl == 0) { \
      float y = s + blin0; \
      out[(size_t)(b0 + ybat) * TT + (tt)] = y; \
      if (FEED) A1h[aidx(100, ybat)] = (__fp16)y; \
    } }

  // ================= teacher-forced phase: 4 barriers/step =================
  for (int t = 0; t < T_IN; t++) {
    __syncthreads();  // A1(h1(t-1), x(t)), A2(h2(t-1)) ready; ybuf(t-1) ready
    L1_PHASE
    if (is_y && t > 0) Y_BODY(t - 1, 0)   // y(t-1) off critical path
    __syncthreads();  // gb2 (L1) ready
    if (is_act) ACT1_BODY
    if (tid >= 464 && tid < 466 && t + 1 < T_IN)
      A1h[aidx(100, tid - 464)] = (__fp16)xrow[tid - 464][t + 1];
    __syncthreads();  // A2(h1(t)) ready; gb2 free
    L2_PHASE
    __syncthreads();  // gb2 (L2) ready
    if (is_act) ACT2_BODY
  }

  // ================= autoregressive phase: 5 barriers/step =================
  for (int t = T_IN; t < TT; t++) {
    __syncthreads();  // ybuf(t-1) ready
    if (is_y) Y_BODY(t - 1, 1)            // y(t-1) -> out + x(t) feed into A1
    __syncthreads();  // A1 x ready
    L1_PHASE
    __syncthreads();
    if (is_act) ACT1_BODY
    __syncthreads();
    L2_PHASE
    __syncthreads();
    if (is_act) ACT2_BODY
  }
  __syncthreads();
  if (is_y) Y_BODY(TT - 1, 0)             // final y
}

extern "C" void kernel_launch(void* const* d_in, const int* in_sizes, int n_in,
                              void* d_out, int out_size, void* d_ws, size_t ws_size,
                              hipStream_t stream) {
  const float* input = (const float*)d_in[0];
  const float* Wih1  = (const float*)d_in[1];
  const float* Whh1  = (const float*)d_in[2];
  const float* bih1  = (const float*)d_in[3];
  const float* bhh1  = (const float*)d_in[4];
  const float* Wih2  = (const float*)d_in[5];
  const float* Whh2  = (const float*)d_in[6];
  const float* bih2  = (const float*)d_in[7];
  const float* bhh2  = (const float*)d_in[8];
  const float* Wlin  = (const float*)d_in[9];
  const float* blin  = (const float*)d_in[10];
  const int*   futp  = (const int*)d_in[11];
  float* out = (float*)d_out;

  dim3 grid(B_TOTAL / NB);  // 256 blocks, 1 per CU
  dim3 block(BLOCK);
  hipLaunchKernelGGL(lstm2_mfma, grid, block, 0, stream,
                     input, Wih1, Whh1, bih1, bhh1, Wih2, Whh2, bih2, bhh2,
                     Wlin, blin, futp, out);
}